// Round 4
// baseline (92.829 us; speedup 1.0000x reference)
//
#include <hip/hip_runtime.h>

typedef _Float16 half2_t __attribute__((ext_vector_type(2)));

#define NBATCH 64
#define HDIM   128
#define NSTEP  64
#define NIN    16
#define HISTP  132   // hist stride in floats: breaks power-of-2 banks, 16B-aligned

__device__ __forceinline__ float sigf(float x) { return 1.f / (1.f + __expf(-x)); }

__device__ __forceinline__ unsigned int h2u(half2_t h) {
    union { half2_t h; unsigned int u; } x; x.h = h; return x.u;
}
__device__ __forceinline__ half2_t u2h(unsigned int u) {
    union { half2_t h; unsigned int u; } x; x.u = u; return x.h;
}

__global__ __launch_bounds__(256) void copy_trip_k(const float4* __restrict__ src,
                                                   float4* __restrict__ dst) {
    int i = blockIdx.x * 256 + threadIdx.x;   // 65536 float4 total
    dst[i] = src[i];
}

// 64 blocks (1/batch) x 1024 threads. Thread t: gate column j = t&511,
// K-half kh = t>>9 (kh=0 -> inp[0..127]=c, kh=1 -> inp[128..255]=h).
// W fragment = 64 packed f16 pairs = 64 VGPRs -> fits the 128-VGPR tier.
__global__ __launch_bounds__(1024) void recur_k(
    const float* __restrict__ emb, const float* __restrict__ Wg,
    const float* __restrict__ bg,  const float* __restrict__ Wl,
    const float* __restrict__ bl,  float* __restrict__ proj_ws) {
    __shared__ __align__(16) unsigned int pack_s[2][128];  // f16 [c(64u)|h(64u)], dbuf
    __shared__ float gpart[2][512];         // per-K-half partial gate sums
    __shared__ float hist[NSTEP * HISTP];   // c_s history (f32), 33.8 KB
    __shared__ float Wl_s[HDIM * NIN];      // 8 KB
    __shared__ float bg_s[512];

    const int b = blockIdx.x, t = threadIdx.x;
    const int j = t & 511, kh = t >> 9;

    // ---- W fragment: rows kh*128 + [0..127], col j, packed f16 ----
    unsigned int Wr[64];
    #pragma unroll
    for (int k = 0; k < 64; ++k) {
        float w0 = Wg[(kh * 128 + 2 * k + 0) * 512 + j];
        float w1 = Wg[(kh * 128 + 2 * k + 1) * 512 + j];
        half2_t hp = { (_Float16)w0, (_Float16)w1 };
        Wr[k] = h2u(hp);
    }

    if (t < 512) bg_s[t] = bg[t];
    for (int i = t; i < HDIM * NIN; i += 1024) Wl_s[i] = Wl[i];
    if (t < 64) {
        float e0 = emb[b * (64 * HDIM) + 2 * t + 0];
        float e1 = emb[b * (64 * HDIM) + 2 * t + 1];
        half2_t hp = { (_Float16)e0, (_Float16)e1 };
        pack_s[0][t] = h2u(hp);             // c-slot <- embedding row 0
    } else if (t < 128) {
        pack_s[0][t] = 0u;                  // h0 = 0
    }
    float c_reg = 0.f;                      // threads 0..127 own c[t]; c0 = 0
    __syncthreads();

    for (int s = 0; s < NSTEP; ++s) {
        // ---- half-dot: 16 uniform ds_read_b128 + 64 fdot2 ----
        const uint4* p4 = (const uint4*)&pack_s[s & 1][kh * 64];
        float a0 = 0.f, a1 = 0.f;
        #pragma unroll
        for (int q = 0; q < 16; ++q) {
            uint4 u = p4[q];
            a0 = __builtin_amdgcn_fdot2(u2h(u.x), u2h(Wr[4 * q + 0]), a0, false);
            a1 = __builtin_amdgcn_fdot2(u2h(u.y), u2h(Wr[4 * q + 1]), a1, false);
            a0 = __builtin_amdgcn_fdot2(u2h(u.z), u2h(Wr[4 * q + 2]), a0, false);
            a1 = __builtin_amdgcn_fdot2(u2h(u.w), u2h(Wr[4 * q + 3]), a1, false);
        }
        gpart[kh][j] = a0 + a1;
        __syncthreads();

        // ---- state update: threads 0..127 own h index t ----
        if (t < HDIM) {
            float fg = sigf(gpart[0][t]       + gpart[1][t]       + bg_s[t]);
            float ig = sigf(gpart[0][128 + t] + gpart[1][128 + t] + bg_s[128 + t]);
            float og = sigf(gpart[0][256 + t] + gpart[1][256 + t] + bg_s[256 + t]);
            float cd = tanhf(gpart[0][384 + t] + gpart[1][384 + t] + bg_s[384 + t]);
            float c_new = fg * c_reg + ig * cd;
            float h_new = og * tanhf(c_new);
            c_reg = c_new;
            hist[s * HISTP + t] = c_new;
            float c_o = __shfl_xor(c_new, 1);
            float h_o = __shfl_xor(h_new, 1);
            if ((t & 1) == 0) {
                half2_t cp = { (_Float16)c_new, (_Float16)c_o };
                half2_t hp = { (_Float16)h_new, (_Float16)h_o };
                int nb = (s + 1) & 1;
                pack_s[nb][(t >> 1)]      = h2u(cp);
                pack_s[nb][64 + (t >> 1)] = h2u(hp);
            }
        }
        __syncthreads();
    }

    // ---- projection: thread t -> (s = t>>4, i = t&15); write 256KB to ws ----
    {
        int s = t >> 4, i = t & 15;
        float acc = bl[i];
        const float4* c4 = (const float4*)&hist[s * HISTP];
        #pragma unroll 8
        for (int h4 = 0; h4 < HDIM / 4; ++h4) {
            float4 cv = c4[h4];
            int h = h4 * 4;
            acc = fmaf(cv.x, Wl_s[(h + 0) * NIN + i], acc);
            acc = fmaf(cv.y, Wl_s[(h + 1) * NIN + i], acc);
            acc = fmaf(cv.z, Wl_s[(h + 2) * NIN + i], acc);
            acc = fmaf(cv.w, Wl_s[(h + 3) * NIN + i], acc);
        }
        proj_ws[b * 1024 + t] = acc;   // [b][s][i]
    }
}

// 4096 blocks (b*64+s) x 256 threads: broadcast proj row to 64 output rows.
__global__ __launch_bounds__(256) void expand_k(const float* __restrict__ proj_ws,
                                                float* __restrict__ out) {
    int blk = blockIdx.x;             // b*64 + s
    int t = threadIdx.x;
    const float4* pj = (const float4*)(proj_ws + blk * 16);
    float4 v = pj[t & 3];             // broadcast 4 lines, L2-hot
    float4* ob = (float4*)(out + (size_t)blk * 1024);  // 64 rows x 16 f = 256 float4
    ob[t] = v;
}

extern "C" void kernel_launch(void* const* d_in, const int* in_sizes, int n_in,
                              void* d_out, int out_size, void* d_ws, size_t ws_size,
                              hipStream_t stream) {
    const float* trip = (const float*)d_in[0];
    // d_in[1] = valid_len : unused by the reference computation
    const float* emb  = (const float*)d_in[2];
    const float* Wg   = (const float*)d_in[3];
    const float* bgp  = (const float*)d_in[4];
    const float* Wlp  = (const float*)d_in[5];
    const float* blp  = (const float*)d_in[6];
    float* out = (float*)d_out;
    float* proj_ws = (float*)d_ws;    // 64*64*16 floats = 256 KB

    // output = [trip (262144 floats) | out (4194304 floats)]
    copy_trip_k<<<256, 256, 0, stream>>>((const float4*)trip, (float4*)out);
    recur_k<<<NBATCH, 1024, 0, stream>>>(emb, Wg, bgp, Wlp, blp, proj_ws);
    expand_k<<<NBATCH * NSTEP, 256, 0, stream>>>(proj_ws, out + 262144);
}